// Round 1
// baseline (773.640 us; speedup 1.0000x reference)
//
#include <hip/hip_runtime.h>
#include <math.h>

#define DIM       4096
#define TOKENS    128        // BS*Q_LEN
#define NKVH      8
#define HD        128
#define MAX_SEQ   4096
#define START_POS 4080       // MAX_SEQ - Q_LEN (fixed by setup_inputs)
#define NQKV      6144       // 4096 q + 1024 k + 1024 v
#define NCHUNK    8
#define CHUNK     512
#define PTILE     16
#define ATT_SCALE 0.08838834764831845f   // 1/sqrt(128)

// ---- workspace layout (float offsets) ----
#define WS_PART_QKV 0           // 4*128*6144 = 3145728 (reused for o-proj partials)
#define WS_Q        3145728     // 128*4096
#define WS_KNEW     3670016     // 128*1024
#define WS_VNEW     3801088     // 128*1024
#define WS_PART_O   3932160     // 512*64*128 = 4194304
#define WS_PART_M   8126464     // 512*64
#define WS_PART_L   8159232     // 512*64
#define WS_ATTN     8192000     // 128*4096
// total = 8716288 floats = 34.9 MB

// ---------------- fp32 GEMM body: M=128, BN=64, BK=32, K-split partials ----------------
// 256 threads; thread (ty,tx) computes rows ty*8..+7, cols tx*4..+3.
__device__ __forceinline__ void gemm128_body(
    const float* __restrict__ xin, const float* __restrict__ W, int ldW, int noff,
    float* __restrict__ part, int partStride, int ncol0, int ks,
    float* __restrict__ xs, float* __restrict__ wsh)
{
    const int t  = threadIdx.x;
    const int ty = t >> 4;
    const int tx = t & 15;
    float acc[8][4];
    #pragma unroll
    for (int m = 0; m < 8; ++m)
        #pragma unroll
        for (int n = 0; n < 4; ++n) acc[m][n] = 0.f;

    const int kbeg = ks * 1024;
    for (int k0 = kbeg; k0 < kbeg + 1024; k0 += 32) {
        #pragma unroll
        for (int i = 0; i < 4; ++i) {
            int f  = t + i * 256;            // x tile: 128x32 = 1024 float4
            int r  = f >> 3;
            int c4 = (f & 7) << 2;
            *(float4*)(xs + r * 36 + c4) =
                *(const float4*)(xin + (size_t)r * DIM + k0 + c4);
        }
        #pragma unroll
        for (int i = 0; i < 2; ++i) {
            int f  = t + i * 256;            // W tile: 32x64 = 512 float4
            int r  = f >> 4;
            int c4 = (f & 15) << 2;
            *(float4*)(wsh + r * 68 + c4) =
                *(const float4*)(W + (size_t)(k0 + r) * ldW + noff + c4);
        }
        __syncthreads();
        #pragma unroll 8
        for (int kk = 0; kk < 32; ++kk) {
            float a[8], b[4];
            #pragma unroll
            for (int m = 0; m < 8; ++m) a[m] = xs[(ty * 8 + m) * 36 + kk];
            #pragma unroll
            for (int n = 0; n < 4; ++n) b[n] = wsh[kk * 68 + tx * 4 + n];
            #pragma unroll
            for (int m = 0; m < 8; ++m)
                #pragma unroll
                for (int n = 0; n < 4; ++n) acc[m][n] = fmaf(a[m], b[n], acc[m][n]);
        }
        __syncthreads();
    }
    #pragma unroll
    for (int m = 0; m < 8; ++m) {
        int row = ty * 8 + m;
        float4 v = make_float4(acc[m][0], acc[m][1], acc[m][2], acc[m][3]);
        *(float4*)(part + (size_t)(ks * 128 + row) * partStride + ncol0 + tx * 4) = v;
    }
}

__global__ __launch_bounds__(256) void qkv_gemm_kernel(
    const float* __restrict__ x, const float* __restrict__ Wq,
    const float* __restrict__ Wk, const float* __restrict__ Wv,
    float* __restrict__ part)
{
    __shared__ float xs[128 * 36];
    __shared__ float wsh[32 * 68];
    int ncol0 = blockIdx.x * 64;
    int ks = blockIdx.y;
    const float* W; int ldW, noff;
    if (ncol0 < 4096)      { W = Wq; ldW = 4096; noff = ncol0; }
    else if (ncol0 < 5120) { W = Wk; ldW = 1024; noff = ncol0 - 4096; }
    else                   { W = Wv; ldW = 1024; noff = ncol0 - 5120; }
    gemm128_body(x, W, ldW, noff, part, NQKV, ncol0, ks, xs, wsh);
}

__global__ __launch_bounds__(256) void oproj_gemm_kernel(
    const float* __restrict__ xin, const float* __restrict__ Wo,
    float* __restrict__ part)
{
    __shared__ float xs[128 * 36];
    __shared__ float wsh[32 * 68];
    int ncol0 = blockIdx.x * 64;
    int ks = blockIdx.y;
    gemm128_body(xin, Wo, 4096, ncol0, part, 4096, ncol0, ks, xs, wsh);
}

__global__ __launch_bounds__(256) void qkv_reduce_kernel(
    const float* __restrict__ part, const float* __restrict__ bq,
    const float* __restrict__ bk, const float* __restrict__ bv,
    float* __restrict__ q, float* __restrict__ k_new, float* __restrict__ v_new)
{
    int gid = blockIdx.x * 256 + threadIdx.x;     // < 128*6144
    int row = gid / NQKV;
    int n   = gid - row * NQKV;
    float s = part[(size_t)row * NQKV + n]
            + part[(size_t)(128 + row) * NQKV + n]
            + part[(size_t)(256 + row) * NQKV + n]
            + part[(size_t)(384 + row) * NQKV + n];
    if (n < 4096)      q[row * 4096 + n] = s + bq[n];
    else if (n < 5120) k_new[row * 1024 + (n - 4096)] = s + bk[n - 4096];
    else               v_new[row * 1024 + (n - 5120)] = s + bv[n - 5120];
}

// ---------------- flash-decoding attention partials ----------------
// block = (b*8 + g)*8 + chunk; 256 threads; 64 q-rows = (rep r)*16 + qpos.
// thread: scoring rows sg*4..+3 (sg=t>>4), position slot si (si=t&15);
// O accumulators: same 4 rows x 8 dims (dims si*8..+7).
__global__ __launch_bounds__(256) void attn_partial_kernel(
    const float* __restrict__ q, const float* __restrict__ k_cache,
    const float* __restrict__ v_cache, const float* __restrict__ k_new,
    const float* __restrict__ v_new, float* __restrict__ part_O,
    float* __restrict__ part_m, float* __restrict__ part_l)
{
    __shared__ float q_lds[64 * 132];
    __shared__ float k_lds[PTILE * 132];
    __shared__ float v_lds[PTILE * 132];
    __shared__ float p_lds[64 * 17];
    const int t = threadIdx.x;
    const int blk = blockIdx.x;
    const int b = blk >> 6;
    const int g = (blk >> 3) & 7;
    const int c = blk & 7;

    #pragma unroll
    for (int i = 0; i < 8; ++i) {
        int f   = t + i * 256;            // 64x128 q tile = 2048 float4
        int row = f >> 5;
        int d0  = (f & 31) << 2;
        int r = row >> 4, qp = row & 15;
        *(float4*)(q_lds + row * 132 + d0) =
            *(const float4*)(q + (size_t)(b * 16 + qp) * DIM + (g * 4 + r) * HD + d0);
    }

    const int sg = t >> 4;
    const int si = t & 15;
    const int dv0 = si * 8;
    float m_reg[4], l_reg[4];
    float4 o[4][2];
    #pragma unroll
    for (int j = 0; j < 4; ++j) {
        m_reg[j] = -INFINITY; l_reg[j] = 0.f;
        o[j][0] = make_float4(0.f, 0.f, 0.f, 0.f);
        o[j][1] = make_float4(0.f, 0.f, 0.f, 0.f);
    }

    for (int tt = 0; tt < CHUNK / PTILE; ++tt) {
        __syncthreads();   // previous tile's consumers done before overwrite
        int base_pos = c * CHUNK + tt * PTILE;
        #pragma unroll
        for (int i = 0; i < 2; ++i) {
            int f  = t + i * 256;          // 16x128 k/v tiles = 512 float4 each
            int p  = f >> 5;
            int d0 = (f & 31) << 2;
            int pos = base_pos + p;
            const float *ksrc, *vsrc;
            if (pos >= START_POS) {
                size_t off = (size_t)(b * 16 + pos - START_POS) * (NKVH * HD) + g * HD + d0;
                ksrc = k_new + off; vsrc = v_new + off;
            } else {
                size_t off = ((size_t)(b * MAX_SEQ + pos) * NKVH + g) * HD + d0;
                ksrc = k_cache + off; vsrc = v_cache + off;
            }
            *(float4*)(k_lds + p * 132 + d0) = *(const float4*)ksrc;
            *(float4*)(v_lds + p * 132 + d0) = *(const float4*)vsrc;
        }
        __syncthreads();

        // QK^T: 4 rows x 1 position per thread
        float sc[4] = {0.f, 0.f, 0.f, 0.f};
        #pragma unroll 4
        for (int d0 = 0; d0 < HD; d0 += 4) {
            float4 bk = *(const float4*)(k_lds + si * 132 + d0);
            #pragma unroll
            for (int j = 0; j < 4; ++j) {
                float4 aq = *(const float4*)(q_lds + (sg * 4 + j) * 132 + d0);
                sc[j] += aq.x * bk.x + aq.y * bk.y + aq.z * bk.z + aq.w * bk.w;
            }
        }

        // online softmax across the 16-lane scoring group (xor masks stay in-group)
        float alpha[4];
        #pragma unroll
        for (int j = 0; j < 4; ++j) {
            float s = sc[j] * ATT_SCALE;
            float tmax = s;
            tmax = fmaxf(tmax, __shfl_xor(tmax, 1));
            tmax = fmaxf(tmax, __shfl_xor(tmax, 2));
            tmax = fmaxf(tmax, __shfl_xor(tmax, 4));
            tmax = fmaxf(tmax, __shfl_xor(tmax, 8));
            float mnew = fmaxf(m_reg[j], tmax);
            alpha[j] = __expf(m_reg[j] - mnew);
            float e = __expf(s - mnew);
            p_lds[(sg * 4 + j) * 17 + si] = e;   // read back by SAME wave in PV
            float tsum = e;
            tsum += __shfl_xor(tsum, 1);
            tsum += __shfl_xor(tsum, 2);
            tsum += __shfl_xor(tsum, 4);
            tsum += __shfl_xor(tsum, 8);
            l_reg[j] = l_reg[j] * alpha[j] + tsum;
            m_reg[j] = mnew;
        }

        #pragma unroll
        for (int j = 0; j < 4; ++j) {
            o[j][0].x *= alpha[j]; o[j][0].y *= alpha[j]; o[j][0].z *= alpha[j]; o[j][0].w *= alpha[j];
            o[j][1].x *= alpha[j]; o[j][1].y *= alpha[j]; o[j][1].z *= alpha[j]; o[j][1].w *= alpha[j];
        }
        #pragma unroll 4
        for (int p = 0; p < PTILE; ++p) {
            float4 v0 = *(const float4*)(v_lds + p * 132 + dv0);
            float4 v1 = *(const float4*)(v_lds + p * 132 + dv0 + 4);
            #pragma unroll
            for (int j = 0; j < 4; ++j) {
                float pw = p_lds[(sg * 4 + j) * 17 + p];
                o[j][0].x += pw * v0.x; o[j][0].y += pw * v0.y;
                o[j][0].z += pw * v0.z; o[j][0].w += pw * v0.w;
                o[j][1].x += pw * v1.x; o[j][1].y += pw * v1.y;
                o[j][1].z += pw * v1.z; o[j][1].w += pw * v1.w;
            }
        }
    }

    #pragma unroll
    for (int j = 0; j < 4; ++j) {
        int row = sg * 4 + j;
        size_t obase = ((size_t)blk * 64 + row) * HD + dv0;
        *(float4*)(part_O + obase) = o[j][0];
        *(float4*)(part_O + obase + 4) = o[j][1];
        if (si == 0) {
            part_m[blk * 64 + row] = m_reg[j];
            part_l[blk * 64 + row] = l_reg[j];
        }
    }
}

__global__ __launch_bounds__(128) void attn_combine_kernel(
    const float* __restrict__ part_O, const float* __restrict__ part_m,
    const float* __restrict__ part_l, float* __restrict__ attn_out)
{
    int bid = blockIdx.x;          // (b*8+g)*64 + row
    int d = threadIdx.x;
    int bg = bid >> 6;
    int row = bid & 63;
    float mc[NCHUNK], lc[NCHUNK];
    float M = -INFINITY;
    #pragma unroll
    for (int cc = 0; cc < NCHUNK; ++cc) {
        mc[cc] = part_m[(bg * NCHUNK + cc) * 64 + row];
        lc[cc] = part_l[(bg * NCHUNK + cc) * 64 + row];
        M = fmaxf(M, mc[cc]);
    }
    float L = 0.f, acc = 0.f;
    #pragma unroll
    for (int cc = 0; cc < NCHUNK; ++cc) {
        float w = __expf(mc[cc] - M);
        L += lc[cc] * w;
        acc += part_O[((size_t)(bg * NCHUNK + cc) * 64 + row) * HD + d] * w;
    }
    int b = bg >> 3, g = bg & 7;
    int r = row >> 4, qp = row & 15;
    attn_out[(size_t)(b * 16 + qp) * DIM + (g * 4 + r) * HD + d] = acc / L;
}

__global__ __launch_bounds__(256) void oproj_reduce_kernel(
    const float* __restrict__ part, const float* __restrict__ bo,
    float* __restrict__ out)
{
    int gid = blockIdx.x * 256 + threadIdx.x;    // < 128*4096
    int n = gid & 4095;
    float s = part[gid] + part[524288 + gid] + part[1048576 + gid] + part[1572864 + gid];
    out[gid] = s + bo[n];
}

extern "C" void kernel_launch(void* const* d_in, const int* in_sizes, int n_in,
                              void* d_out, int out_size, void* d_ws, size_t ws_size,
                              hipStream_t stream)
{
    const float* x  = (const float*)d_in[0];
    const float* kc = (const float*)d_in[1];
    const float* vc = (const float*)d_in[2];
    const float* Wq = (const float*)d_in[3];
    const float* bq = (const float*)d_in[4];
    const float* Wk = (const float*)d_in[5];
    const float* bk = (const float*)d_in[6];
    const float* Wv = (const float*)d_in[7];
    const float* bv = (const float*)d_in[8];
    const float* Wo = (const float*)d_in[9];
    const float* bo = (const float*)d_in[10];
    float* out = (float*)d_out;
    float* ws  = (float*)d_ws;

    qkv_gemm_kernel<<<dim3(96, 4), 256, 0, stream>>>(x, Wq, Wk, Wv, ws + WS_PART_QKV);
    qkv_reduce_kernel<<<3072, 256, 0, stream>>>(ws + WS_PART_QKV, bq, bk, bv,
                                                ws + WS_Q, ws + WS_KNEW, ws + WS_VNEW);
    attn_partial_kernel<<<512, 256, 0, stream>>>(ws + WS_Q, kc, vc,
                                                 ws + WS_KNEW, ws + WS_VNEW,
                                                 ws + WS_PART_O, ws + WS_PART_M, ws + WS_PART_L);
    attn_combine_kernel<<<4096, 128, 0, stream>>>(ws + WS_PART_O, ws + WS_PART_M,
                                                  ws + WS_PART_L, ws + WS_ATTN);
    oproj_gemm_kernel<<<dim3(64, 4), 256, 0, stream>>>(ws + WS_ATTN, Wo, ws + WS_PART_QKV);
    oproj_reduce_kernel<<<2048, 256, 0, stream>>>(ws + WS_PART_QKV, bo, out);
}

// Round 2
// 495.912 us; speedup vs baseline: 1.5600x; 1.5600x over previous
//
#include <hip/hip_runtime.h>
#include <math.h>

#define DIM       4096
#define NKVH      8
#define HD        128
#define MAX_SEQ   4096
#define START_POS 4080
#define NQKV      6144
#define NCHUNK    8
#define CHUNK     512
#define ATT_SCALE 0.08838834764831845f

// ---- workspace layout (float offsets) ----
#define WS_PART   0           // 3145728  (qkv partials; reused for o-proj)
#define WS_QH     3145728     // 262144 floats = 524288 ushorts
#define WS_QL     3407872
#define WS_KNEW   3670016     // 131072
#define WS_VNEW   3801088     // 131072
#define WS_PARTO  3932160     // 4194304
#define WS_PM     8126464     // 32768
#define WS_PL     8159232     // 32768
#define WS_ATH    8192000     // 262144
#define WS_ATL    8454144     // 262144
// x hi/lo overlapped into PARTO region (consumed before attn writes partO)
#define WS_XH     WS_PARTO
#define WS_XL     (WS_PARTO + 262144)
// total = 8716288 floats = 34.87 MB (same as round-1 footprint)

typedef __bf16 bf16x8 __attribute__((ext_vector_type(8)));
typedef float  f32x4  __attribute__((ext_vector_type(4)));
typedef unsigned int uintx4 __attribute__((ext_vector_type(4)));

__device__ __forceinline__ unsigned short f2bf(float f) {
    union { float f; unsigned int u; } v; v.f = f;
    unsigned int r = v.u + 0x7FFFu + ((v.u >> 16) & 1u);
    return (unsigned short)(r >> 16);
}
__device__ __forceinline__ float bf2f(unsigned short h) {
    union { unsigned int u; float f; } v; v.u = ((unsigned int)h) << 16;
    return v.f;
}
__device__ __forceinline__ void splitbf(float f, unsigned short &h, unsigned short &l) {
    h = f2bf(f);
    l = f2bf(f - bf2f(h));
}
__device__ __forceinline__ bf16x8 ldsfrag(const unsigned short* p) {
    uintx4 u = *(const uintx4*)p;
    return __builtin_bit_cast(bf16x8, u);
}
#define MFMA16(a,b,c) __builtin_amdgcn_mfma_f32_16x16x32_bf16(a, b, c, 0, 0, 0)

// ---------------- split x -> bf16 hi/lo ----------------
__global__ __launch_bounds__(256) void split_x_kernel(
    const float* __restrict__ x, unsigned short* __restrict__ xh,
    unsigned short* __restrict__ xl, int n)
{
    int i = blockIdx.x * 256 + threadIdx.x;
    if (i < n) { unsigned short h, l; splitbf(x[i], h, l); xh[i] = h; xl[i] = l; }
}

// ---------------- split-bf16 MFMA GEMM body ----------------
// M=128 (all tokens), BN=64, BK=64, K-range 1024 per ks. 256 thr / 4 waves.
// wave w: m-tiles {2w,2w+1} x 4 n-tiles, 16x16x32 MFMA, 3 per product (hi/lo).
__device__ __forceinline__ void gemm_body(
    const unsigned short* __restrict__ Ah, const unsigned short* __restrict__ Al,
    const float* __restrict__ W, int ldW, int noff,
    float* __restrict__ part, int partStride, int ncol0, int ks,
    unsigned short* Ahs, unsigned short* Als,
    unsigned short* Bhs, unsigned short* Bls)
{
    const int t = threadIdx.x;
    const int w = t >> 6, lane = t & 63, l15 = lane & 15, quad = lane >> 4;
    f32x4 acc[2][4];
    #pragma unroll
    for (int i = 0; i < 2; ++i)
        #pragma unroll
        for (int nt = 0; nt < 4; ++nt) acc[i][nt] = (f32x4){0.f, 0.f, 0.f, 0.f};

    const int k0base = ks * 1024;
    uintx4 areg_h[4], areg_l[4];
    float4 wreg[4];

    auto LOAD = [&](int it) {
        int k0 = k0base + it * 64;
        #pragma unroll
        for (int i = 0; i < 4; ++i) {
            int f = t + i * 256;
            int row = f >> 3, c0 = (f & 7) << 3;
            size_t off = (size_t)row * DIM + k0 + c0;
            areg_h[i] = *(const uintx4*)(Ah + off);
            areg_l[i] = *(const uintx4*)(Al + off);
        }
        #pragma unroll
        for (int i = 0; i < 4; ++i) {
            int f = t + i * 256;
            int kk = f >> 4, n0 = (f & 15) << 2;
            wreg[i] = *(const float4*)(W + (size_t)(k0 + kk) * ldW + noff + n0);
        }
    };

    LOAD(0);
    for (int it = 0; it < 16; ++it) {
        __syncthreads();
        #pragma unroll
        for (int i = 0; i < 4; ++i) {
            int f = t + i * 256;
            int row = f >> 3, c0 = (f & 7) << 3;
            *(uintx4*)(Ahs + row * 72 + c0) = areg_h[i];
            *(uintx4*)(Als + row * 72 + c0) = areg_l[i];
        }
        #pragma unroll
        for (int i = 0; i < 4; ++i) {
            int f = t + i * 256;
            int kk = f >> 4, n0 = (f & 15) << 2;
            float vv[4] = {wreg[i].x, wreg[i].y, wreg[i].z, wreg[i].w};
            #pragma unroll
            for (int j = 0; j < 4; ++j) {
                unsigned short h, l; splitbf(vv[j], h, l);
                Bhs[(n0 + j) * 72 + kk] = h;   // transposed: [n][k]
                Bls[(n0 + j) * 72 + kk] = l;
            }
        }
        __syncthreads();
        if (it < 15) LOAD(it + 1);
        #pragma unroll
        for (int kt = 0; kt < 2; ++kt) {
            int ko = kt * 32 + quad * 8;
            bf16x8 ah0 = ldsfrag(Ahs + ((2*w+0)*16 + l15) * 72 + ko);
            bf16x8 ah1 = ldsfrag(Ahs + ((2*w+1)*16 + l15) * 72 + ko);
            bf16x8 al0 = ldsfrag(Als + ((2*w+0)*16 + l15) * 72 + ko);
            bf16x8 al1 = ldsfrag(Als + ((2*w+1)*16 + l15) * 72 + ko);
            #pragma unroll
            for (int nt = 0; nt < 4; ++nt) {
                bf16x8 bh = ldsfrag(Bhs + (nt*16 + l15) * 72 + ko);
                bf16x8 bl = ldsfrag(Bls + (nt*16 + l15) * 72 + ko);
                acc[0][nt] = MFMA16(ah0, bh, acc[0][nt]);
                acc[0][nt] = MFMA16(ah0, bl, acc[0][nt]);
                acc[0][nt] = MFMA16(al0, bh, acc[0][nt]);
                acc[1][nt] = MFMA16(ah1, bh, acc[1][nt]);
                acc[1][nt] = MFMA16(ah1, bl, acc[1][nt]);
                acc[1][nt] = MFMA16(al1, bh, acc[1][nt]);
            }
        }
    }
    #pragma unroll
    for (int i = 0; i < 2; ++i)
        #pragma unroll
        for (int nt = 0; nt < 4; ++nt)
            #pragma unroll
            for (int r = 0; r < 4; ++r) {
                int row = (2*w + i) * 16 + quad * 4 + r;       // C/D: row=quad*4+reg
                int col = ncol0 + nt * 16 + l15;               //      col=lane&15
                part[(size_t)(ks * 128 + row) * partStride + col] = acc[i][nt][r];
            }
}

__global__ __launch_bounds__(256) void qkv_gemm_kernel(
    const unsigned short* __restrict__ xh, const unsigned short* __restrict__ xl,
    const float* __restrict__ Wq, const float* __restrict__ Wk,
    const float* __restrict__ Wv, float* __restrict__ part)
{
    __shared__ unsigned short Ahs[128 * 72], Als[128 * 72];
    __shared__ unsigned short Bhs[64 * 72],  Bls[64 * 72];
    int ncol0 = blockIdx.x * 64;
    int ks = blockIdx.y;
    const float* W; int ldW, noff;
    if (ncol0 < 4096)      { W = Wq; ldW = 4096; noff = ncol0; }
    else if (ncol0 < 5120) { W = Wk; ldW = 1024; noff = ncol0 - 4096; }
    else                   { W = Wv; ldW = 1024; noff = ncol0 - 5120; }
    gemm_body(xh, xl, W, ldW, noff, part, NQKV, ncol0, ks, Ahs, Als, Bhs, Bls);
}

__global__ __launch_bounds__(256) void oproj_gemm_kernel(
    const unsigned short* __restrict__ ah, const unsigned short* __restrict__ al,
    const float* __restrict__ Wo, float* __restrict__ part)
{
    __shared__ unsigned short Ahs[128 * 72], Als[128 * 72];
    __shared__ unsigned short Bhs[64 * 72],  Bls[64 * 72];
    int ncol0 = blockIdx.x * 64;
    int ks = blockIdx.y;
    gemm_body(ah, al, Wo, 4096, ncol0, part, 4096, ncol0, ks, Ahs, Als, Bhs, Bls);
}

__global__ __launch_bounds__(256) void qkv_reduce_kernel(
    const float* __restrict__ part, const float* __restrict__ bq,
    const float* __restrict__ bk, const float* __restrict__ bv,
    unsigned short* __restrict__ qh, unsigned short* __restrict__ ql,
    float* __restrict__ k_new, float* __restrict__ v_new)
{
    int gid = blockIdx.x * 256 + threadIdx.x;     // < 128*6144
    int row = gid / NQKV;
    int n   = gid - row * NQKV;
    float s = part[(size_t)row * NQKV + n]
            + part[(size_t)(128 + row) * NQKV + n]
            + part[(size_t)(256 + row) * NQKV + n]
            + part[(size_t)(384 + row) * NQKV + n];
    if (n < 4096) {
        float v = s + bq[n];
        unsigned short h, l; splitbf(v, h, l);
        qh[row * 4096 + n] = h; ql[row * 4096 + n] = l;
    } else if (n < 5120) k_new[row * 1024 + (n - 4096)] = s + bk[n - 4096];
    else                 v_new[row * 1024 + (n - 5120)] = s + bv[n - 5120];
}

// ---------------- MFMA flash-decoding attention ----------------
// block = (b*8+g)*8 + chunk(512 pos). 4 waves; wave w = rep-head w (16 q rows).
// Per 32-pos tile: S = Q*K^T (split-bf16), online softmax in C-layout,
// P through per-wave LDS transpose, O += P*V (split-bf16).
__global__ __launch_bounds__(256) void attn_partial2_kernel(
    const unsigned short* __restrict__ qhp, const unsigned short* __restrict__ qlp,
    const float* __restrict__ kc, const float* __restrict__ vc,
    const float* __restrict__ knew, const float* __restrict__ vnew,
    float* __restrict__ part_O, float* __restrict__ part_m, float* __restrict__ part_l)
{
    __shared__ unsigned short Kh[32 * 136], Kl[32 * 136];
    __shared__ unsigned short Vh[128 * 40], Vl[128 * 40];   // V transposed [d][p]
    __shared__ unsigned short Ph[4 * 16 * 40], Pl[4 * 16 * 40];
    const int t = threadIdx.x;
    const int w = t >> 6, lane = t & 63, l15 = lane & 15, quad = lane >> 4;
    const int blk = blockIdx.x;
    const int b = blk >> 6, g = (blk >> 3) & 7, c = blk & 7;

    // Q fragments in registers: A[m=qpos=l15][k=quad*8+j], head g*4+w
    bf16x8 qhf[4], qlf[4];
    {
        size_t base = (size_t)(b * 16 + l15) * DIM + (g * 4 + w) * HD + quad * 8;
        #pragma unroll
        for (int kt = 0; kt < 4; ++kt) {
            qhf[kt] = ldsfrag(qhp + base + kt * 32);
            qlf[kt] = ldsfrag(qlp + base + kt * 32);
        }
    }

    float m_run[4], l_run[4];
    f32x4 oacc[8];
    #pragma unroll
    for (int r = 0; r < 4; ++r) { m_run[r] = -INFINITY; l_run[r] = 0.f; }
    #pragma unroll
    for (int d = 0; d < 8; ++d) oacc[d] = (f32x4){0.f, 0.f, 0.f, 0.f};

    float4 kreg[4], vreg[4];
    auto LOADKV = [&](int it) {
        #pragma unroll
        for (int i = 0; i < 4; ++i) {
            int f = t + i * 256;
            int pos = f >> 5, d0 = (f & 31) << 2;
            int pg = c * CHUNK + it * 32 + pos;
            const float *ksrc, *vsrc;
            if (pg >= START_POS) {
                size_t off = (size_t)(b * 16 + pg - START_POS) * (NKVH * HD) + g * HD + d0;
                ksrc = knew + off; vsrc = vnew + off;
            } else {
                size_t off = ((size_t)(b * MAX_SEQ + pg) * NKVH + g) * HD + d0;
                ksrc = kc + off; vsrc = vc + off;
            }
            kreg[i] = *(const float4*)ksrc;
            vreg[i] = *(const float4*)vsrc;
        }
    };

    unsigned short* phw = Ph + w * 640;
    unsigned short* plw = Pl + w * 640;

    LOADKV(0);
    for (int it = 0; it < CHUNK / 32; ++it) {
        __syncthreads();
        #pragma unroll
        for (int i = 0; i < 4; ++i) {
            int f = t + i * 256;
            int pos = f >> 5, d0 = (f & 31) << 2;
            float kv[4] = {kreg[i].x, kreg[i].y, kreg[i].z, kreg[i].w};
            float vv[4] = {vreg[i].x, vreg[i].y, vreg[i].z, vreg[i].w};
            unsigned short h0,l0,h1,l1,h2,l2,h3,l3;
            splitbf(kv[0],h0,l0); splitbf(kv[1],h1,l1);
            splitbf(kv[2],h2,l2); splitbf(kv[3],h3,l3);
            *(ushort4*)&Kh[pos * 136 + d0] = make_ushort4(h0,h1,h2,h3);
            *(ushort4*)&Kl[pos * 136 + d0] = make_ushort4(l0,l1,l2,l3);
            #pragma unroll
            for (int j = 0; j < 4; ++j) {
                unsigned short h, l; splitbf(vv[j], h, l);
                Vh[(d0 + j) * 40 + pos] = h;
                Vl[(d0 + j) * 40 + pos] = l;
            }
        }
        __syncthreads();
        if (it + 1 < CHUNK / 32) LOADKV(it + 1);

        // S = Q K^T over 32 positions (2 n-tiles)
        f32x4 sacc[2];
        sacc[0] = (f32x4){0.f,0.f,0.f,0.f};
        sacc[1] = (f32x4){0.f,0.f,0.f,0.f};
        #pragma unroll
        for (int nt = 0; nt < 2; ++nt)
            #pragma unroll
            for (int kt = 0; kt < 4; ++kt) {
                const unsigned short* kp = &Kh[(nt*16 + l15) * 136 + kt*32 + quad*8];
                const unsigned short* lp = &Kl[(nt*16 + l15) * 136 + kt*32 + quad*8];
                bf16x8 bh = ldsfrag(kp), bl = ldsfrag(lp);
                sacc[nt] = MFMA16(qhf[kt], bh, sacc[nt]);
                sacc[nt] = MFMA16(qhf[kt], bl, sacc[nt]);
                sacc[nt] = MFMA16(qlf[kt], bh, sacc[nt]);
            }

        // online softmax; rows (qpos) = quad*4+r live across the quad's 16 lanes
        float e0[4], e1[4], alpha[4];
        #pragma unroll
        for (int r = 0; r < 4; ++r) {
            float s0 = sacc[0][r] * ATT_SCALE;
            float s1 = sacc[1][r] * ATT_SCALE;
            float mx = fmaxf(s0, s1);
            mx = fmaxf(mx, __shfl_xor(mx, 1));
            mx = fmaxf(mx, __shfl_xor(mx, 2));
            mx = fmaxf(mx, __shfl_xor(mx, 4));
            mx = fmaxf(mx, __shfl_xor(mx, 8));
            float mnew = fmaxf(m_run[r], mx);
            alpha[r] = __expf(m_run[r] - mnew);
            e0[r] = __expf(s0 - mnew);
            e1[r] = __expf(s1 - mnew);
            float sum = e0[r] + e1[r];
            sum += __shfl_xor(sum, 1);
            sum += __shfl_xor(sum, 2);
            sum += __shfl_xor(sum, 4);
            sum += __shfl_xor(sum, 8);
            l_run[r] = l_run[r] * alpha[r] + sum;
            m_run[r] = mnew;
        }
        #pragma unroll
        for (int d = 0; d < 8; ++d)
            #pragma unroll
            for (int r = 0; r < 4; ++r) oacc[d][r] *= alpha[r];

        // P -> per-wave LDS (transpose C-layout -> A-layout), split hi/lo
        #pragma unroll
        for (int r = 0; r < 4; ++r) {
            unsigned short h, l;
            splitbf(e0[r], h, l);
            phw[(quad*4 + r) * 40 + l15] = h;
            plw[(quad*4 + r) * 40 + l15] = l;
            splitbf(e1[r], h, l);
            phw[(quad*4 + r) * 40 + 16 + l15] = h;
            plw[(quad*4 + r) * 40 + 16 + l15] = l;
        }
        bf16x8 pah = ldsfrag(phw + l15 * 40 + quad * 8);
        bf16x8 pal = ldsfrag(plw + l15 * 40 + quad * 8);

        // O += P V
        #pragma unroll
        for (int d = 0; d < 8; ++d) {
            bf16x8 vh = ldsfrag(&Vh[(d*16 + l15) * 40 + quad * 8]);
            bf16x8 vl = ldsfrag(&Vl[(d*16 + l15) * 40 + quad * 8]);
            oacc[d] = MFMA16(pah, vh, oacc[d]);
            oacc[d] = MFMA16(pah, vl, oacc[d]);
            oacc[d] = MFMA16(pal, vh, oacc[d]);
        }
    }

    #pragma unroll
    for (int d = 0; d < 8; ++d)
        #pragma unroll
        for (int r = 0; r < 4; ++r)
            part_O[((size_t)blk * 64 + w * 16 + quad * 4 + r) * HD + d * 16 + l15] = oacc[d][r];
    if (l15 == 0) {
        #pragma unroll
        for (int r = 0; r < 4; ++r) {
            part_m[blk * 64 + w * 16 + quad * 4 + r] = m_run[r];
            part_l[blk * 64 + w * 16 + quad * 4 + r] = l_run[r];
        }
    }
}

__global__ __launch_bounds__(128) void attn_combine_kernel(
    const float* __restrict__ part_O, const float* __restrict__ part_m,
    const float* __restrict__ part_l, unsigned short* __restrict__ ah,
    unsigned short* __restrict__ al)
{
    int bid = blockIdx.x;          // (b*8+g)*64 + row
    int d = threadIdx.x;
    int bg = bid >> 6;
    int row = bid & 63;
    float mc[NCHUNK], lc[NCHUNK];
    float M = -INFINITY;
    #pragma unroll
    for (int cc = 0; cc < NCHUNK; ++cc) {
        mc[cc] = part_m[(bg * NCHUNK + cc) * 64 + row];
        lc[cc] = part_l[(bg * NCHUNK + cc) * 64 + row];
        M = fmaxf(M, mc[cc]);
    }
    float L = 0.f, acc = 0.f;
    #pragma unroll
    for (int cc = 0; cc < NCHUNK; ++cc) {
        float wgt = __expf(mc[cc] - M);
        L += lc[cc] * wgt;
        acc += part_O[((size_t)(bg * NCHUNK + cc) * 64 + row) * HD + d] * wgt;
    }
    int b = bg >> 3, g = bg & 7;
    int r = row >> 4, qp = row & 15;
    float v = acc / L;
    unsigned short h, l; splitbf(v, h, l);
    size_t idx = (size_t)(b * 16 + qp) * DIM + (g * 4 + r) * HD + d;
    ah[idx] = h; al[idx] = l;
}

__global__ __launch_bounds__(256) void oproj_reduce_kernel(
    const float* __restrict__ part, const float* __restrict__ bo,
    float* __restrict__ out)
{
    int gid = blockIdx.x * 256 + threadIdx.x;    // < 128*4096
    int n = gid & 4095;
    float s = part[gid] + part[524288 + gid] + part[1048576 + gid] + part[1572864 + gid];
    out[gid] = s + bo[n];
}

extern "C" void kernel_launch(void* const* d_in, const int* in_sizes, int n_in,
                              void* d_out, int out_size, void* d_ws, size_t ws_size,
                              hipStream_t stream)
{
    const float* x  = (const float*)d_in[0];
    const float* kc = (const float*)d_in[1];
    const float* vc = (const float*)d_in[2];
    const float* Wq = (const float*)d_in[3];
    const float* bq = (const float*)d_in[4];
    const float* Wk = (const float*)d_in[5];
    const float* bk = (const float*)d_in[6];
    const float* Wv = (const float*)d_in[7];
    const float* bv = (const float*)d_in[8];
    const float* Wo = (const float*)d_in[9];
    const float* bo = (const float*)d_in[10];
    float* out = (float*)d_out;
    float* ws  = (float*)d_ws;

    unsigned short* xh = (unsigned short*)(ws + WS_XH);
    unsigned short* xl = (unsigned short*)(ws + WS_XL);
    unsigned short* qh = (unsigned short*)(ws + WS_QH);
    unsigned short* ql = (unsigned short*)(ws + WS_QL);
    unsigned short* ath = (unsigned short*)(ws + WS_ATH);
    unsigned short* atl = (unsigned short*)(ws + WS_ATL);

    split_x_kernel<<<2048, 256, 0, stream>>>(x, xh, xl, 524288);
    qkv_gemm_kernel<<<dim3(96, 4), 256, 0, stream>>>(xh, xl, Wq, Wk, Wv, ws + WS_PART);
    qkv_reduce_kernel<<<3072, 256, 0, stream>>>(ws + WS_PART, bq, bk, bv,
                                                qh, ql, ws + WS_KNEW, ws + WS_VNEW);
    attn_partial2_kernel<<<512, 256, 0, stream>>>(qh, ql, kc, vc,
                                                  ws + WS_KNEW, ws + WS_VNEW,
                                                  ws + WS_PARTO, ws + WS_PM, ws + WS_PL);
    attn_combine_kernel<<<4096, 128, 0, stream>>>(ws + WS_PARTO, ws + WS_PM,
                                                  ws + WS_PL, ath, atl);
    oproj_gemm_kernel<<<dim3(64, 4), 256, 0, stream>>>(ath, atl, Wo, ws + WS_PART);
    oproj_reduce_kernel<<<2048, 256, 0, stream>>>(ws + WS_PART, bo, out);
}

// Round 3
// 435.465 us; speedup vs baseline: 1.7766x; 1.1388x over previous
//
#include <hip/hip_runtime.h>
#include <math.h>

#define DIM       4096
#define NKVH      8
#define HD        128
#define MAX_SEQ   4096
#define START_POS 4080
#define NQKV      6144
#define NCHUNK    8
#define CHUNK     512
#define KS        8
#define ATT_SCALE 0.08838834764831845f

// ---- workspace layout (float offsets) ----
#define WS_PART   0           // 8*128*6144 = 6291456 (qkv partials; attn partO + oproj partials alias)
#define WS_QH     6291456     // 262144 fl = 524288 ushorts
#define WS_QL     6553600
#define WS_KNEW   6815744     // 131072
#define WS_VNEW   6946816     // 131072
#define WS_PM     7077888     // 32768
#define WS_PL     7110656     // 32768
#define WS_ATH    7143424     // 262144
#define WS_ATL    7405568     // 262144
#define WS_XH     7667712     // 262144
#define WS_XL     7929856     // 262144
#define WS_PARTO  WS_PART     // 512*64*128 = 4194304 <= 6291456, stream-ordered reuse
// total = 8192000 floats = 32.8 MB

typedef __bf16 bf16x8 __attribute__((ext_vector_type(8)));
typedef float  f32x4  __attribute__((ext_vector_type(4)));
typedef unsigned int uintx4 __attribute__((ext_vector_type(4)));

__device__ __forceinline__ unsigned short f2bf(float f) {
    union { float f; unsigned int u; } v; v.f = f;
    unsigned int r = v.u + 0x7FFFu + ((v.u >> 16) & 1u);
    return (unsigned short)(r >> 16);
}
__device__ __forceinline__ float bf2f(unsigned short h) {
    union { unsigned int u; float f; } v; v.u = ((unsigned int)h) << 16;
    return v.f;
}
__device__ __forceinline__ void splitbf(float f, unsigned short &h, unsigned short &l) {
    h = f2bf(f);
    l = f2bf(f - bf2f(h));
}
__device__ __forceinline__ bf16x8 ldsfrag(const unsigned short* p) {
    uintx4 u = *(const uintx4*)p;
    return __builtin_bit_cast(bf16x8, u);
}
// 8B-aligned fragment load (two b64 reads) for stride-68 rows
__device__ __forceinline__ bf16x8 ldsfrag2(const unsigned short* p) {
    union { uint2 u2[2]; bf16x8 v; } u;
    u.u2[0] = *(const uint2*)p;
    u.u2[1] = *(const uint2*)(p + 4);
    return u.v;
}
#define MFMA16(a,b,c) __builtin_amdgcn_mfma_f32_16x16x32_bf16(a, b, c, 0, 0, 0)
#define VCOMP(v,j) ((j)==0?(v).x:((j)==1?(v).y:((j)==2?(v).z:(v).w)))

// ---------------- split x -> bf16 hi/lo ----------------
__global__ __launch_bounds__(256) void split_x_kernel(
    const float* __restrict__ x, unsigned short* __restrict__ xh,
    unsigned short* __restrict__ xl, int n)
{
    int i = blockIdx.x * 256 + threadIdx.x;
    if (i < n) { unsigned short h, l; splitbf(x[i], h, l); xh[i] = h; xl[i] = l; }
}

// ---------------- GEMM: A = split-bf16 (hi/lo), B = W fp32 -> plain bf16 ----------------
// M=128, BN=64, BK=64, 8 K-iters of 64 (K-range 512 per ks). 256 thr / 4 waves.
// wave w: m-tiles {2w,2w+1} x 4 n-tiles; 2 MFMA per product (Ah*B + Al*B).
__device__ __forceinline__ void gemm_body(
    const unsigned short* __restrict__ Ah, const unsigned short* __restrict__ Al,
    const float* __restrict__ W, int ldW, int noff,
    float* __restrict__ part, int partStride, int ncol0, int ks,
    unsigned short* Ahs, unsigned short* Als, unsigned short* Bs)
{
    const int t = threadIdx.x;
    const int w = t >> 6, lane = t & 63, l15 = lane & 15, quad = lane >> 4;
    f32x4 acc[2][4];
    #pragma unroll
    for (int i = 0; i < 2; ++i)
        #pragma unroll
        for (int nt = 0; nt < 4; ++nt) acc[i][nt] = (f32x4){0.f, 0.f, 0.f, 0.f};

    const int k0base = ks * 512;
    uintx4 areg_h[4], areg_l[4];
    float4 wreg[4];

    auto LOAD = [&](int it) {
        int k0 = k0base + it * 64;
        #pragma unroll
        for (int i = 0; i < 4; ++i) {
            int f = t + i * 256;                 // 128x64 A tile = 1024 x8-vectors
            int row = f >> 3, c0 = (f & 7) << 3;
            size_t off = (size_t)row * DIM + k0 + c0;
            areg_h[i] = *(const uintx4*)(Ah + off);
            areg_l[i] = *(const uintx4*)(Al + off);
        }
        #pragma unroll
        for (int i = 0; i < 4; ++i) {
            int kk = (t >> 4) + 16 * i;          // 64x64 W tile = 1024 float4
            int n0 = (t & 15) << 2;
            wreg[i] = *(const float4*)(W + (size_t)(k0 + kk) * ldW + noff + n0);
        }
    };

    LOAD(0);
    for (int it = 0; it < 8; ++it) {
        __syncthreads();
        #pragma unroll
        for (int i = 0; i < 4; ++i) {
            int f = t + i * 256;
            int row = f >> 3, c0 = (f & 7) << 3;
            *(uintx4*)(Ahs + row * 72 + c0) = areg_h[i];
            *(uintx4*)(Als + row * 72 + c0) = areg_l[i];
        }
        {
            int n0 = (t & 15) << 2;
            #pragma unroll
            for (int i = 0; i < 4; ++i) {
                int kk = (t >> 4) + 16 * i;
                #pragma unroll
                for (int j = 0; j < 4; ++j)
                    Bs[(n0 + j) * 68 + kk] = f2bf(VCOMP(wreg[i], j));   // [n][k]
            }
        }
        __syncthreads();
        if (it < 7) LOAD(it + 1);
        #pragma unroll
        for (int kt = 0; kt < 2; ++kt) {
            int ko = kt * 32 + quad * 8;
            bf16x8 ah0 = ldsfrag(Ahs + ((2*w+0)*16 + l15) * 72 + ko);
            bf16x8 ah1 = ldsfrag(Ahs + ((2*w+1)*16 + l15) * 72 + ko);
            bf16x8 al0 = ldsfrag(Als + ((2*w+0)*16 + l15) * 72 + ko);
            bf16x8 al1 = ldsfrag(Als + ((2*w+1)*16 + l15) * 72 + ko);
            #pragma unroll
            for (int nt = 0; nt < 4; ++nt) {
                bf16x8 b = ldsfrag2(Bs + (nt*16 + l15) * 68 + ko);
                acc[0][nt] = MFMA16(ah0, b, acc[0][nt]);
                acc[0][nt] = MFMA16(al0, b, acc[0][nt]);
                acc[1][nt] = MFMA16(ah1, b, acc[1][nt]);
                acc[1][nt] = MFMA16(al1, b, acc[1][nt]);
            }
        }
    }
    #pragma unroll
    for (int i = 0; i < 2; ++i)
        #pragma unroll
        for (int nt = 0; nt < 4; ++nt)
            #pragma unroll
            for (int r = 0; r < 4; ++r) {
                int row = (2*w + i) * 16 + quad * 4 + r;     // C/D: row=quad*4+reg
                int col = ncol0 + nt * 16 + l15;             //      col=lane&15
                part[(size_t)(ks * 128 + row) * partStride + col] = acc[i][nt][r];
            }
}

__global__ __launch_bounds__(256) void qkv_gemm_kernel(
    const unsigned short* __restrict__ xh, const unsigned short* __restrict__ xl,
    const float* __restrict__ Wq, const float* __restrict__ Wk,
    const float* __restrict__ Wv, float* __restrict__ part)
{
    __shared__ unsigned short Ahs[128 * 72], Als[128 * 72];
    __shared__ unsigned short Bs[64 * 68];
    int ncol0 = blockIdx.x * 64;
    int ks = blockIdx.y;
    const float* W; int ldW, noff;
    if (ncol0 < 4096)      { W = Wq; ldW = 4096; noff = ncol0; }
    else if (ncol0 < 5120) { W = Wk; ldW = 1024; noff = ncol0 - 4096; }
    else                   { W = Wv; ldW = 1024; noff = ncol0 - 5120; }
    gemm_body(xh, xl, W, ldW, noff, part, NQKV, ncol0, ks, Ahs, Als, Bs);
}

__global__ __launch_bounds__(256) void oproj_gemm_kernel(
    const unsigned short* __restrict__ ah, const unsigned short* __restrict__ al,
    const float* __restrict__ Wo, float* __restrict__ part)
{
    __shared__ unsigned short Ahs[128 * 72], Als[128 * 72];
    __shared__ unsigned short Bs[64 * 68];
    int ncol0 = blockIdx.x * 64;
    int ks = blockIdx.y;
    gemm_body(ah, al, Wo, 4096, ncol0, part, 4096, ncol0, ks, Ahs, Als, Bs);
}

__global__ __launch_bounds__(256) void qkv_reduce_kernel(
    const float* __restrict__ part, const float* __restrict__ bq,
    const float* __restrict__ bk, const float* __restrict__ bv,
    unsigned short* __restrict__ qh, unsigned short* __restrict__ ql,
    float* __restrict__ k_new, float* __restrict__ v_new)
{
    int gid = blockIdx.x * 256 + threadIdx.x;     // < 128*6144
    int row = gid / NQKV;
    int n   = gid - row * NQKV;
    float s = 0.f;
    #pragma unroll
    for (int j = 0; j < KS; ++j)
        s += part[(size_t)(j * 128 + row) * NQKV + n];
    if (n < 4096) {
        float v = s + bq[n];
        unsigned short h, l; splitbf(v, h, l);
        qh[row * 4096 + n] = h; ql[row * 4096 + n] = l;
    } else if (n < 5120) k_new[row * 1024 + (n - 4096)] = s + bk[n - 4096];
    else                 v_new[row * 1024 + (n - 5120)] = s + bv[n - 5120];
}

// ---------------- MFMA flash-decoding attention (bf16 K/V/P, split-bf16 Q) ----------------
// block = (b*8+g)*8 + chunk(512 pos). 4 waves; wave w = rep-head w (16 q rows).
// pos-slot permutation pi(pos) = (pos&7)*4 + (pos>>3), applied to BOTH P and V^T.
__global__ __launch_bounds__(256) void attn_partial3_kernel(
    const unsigned short* __restrict__ qhp, const unsigned short* __restrict__ qlp,
    const float* __restrict__ kc, const float* __restrict__ vc,
    const float* __restrict__ knew, const float* __restrict__ vnew,
    float* __restrict__ part_O, float* __restrict__ part_m, float* __restrict__ part_l)
{
    __shared__ unsigned short Kb[32 * 136];       // [pos][d] bf16
    __shared__ unsigned short Vt[128 * 36];       // [d][slot] bf16 (pos permuted)
    __shared__ unsigned short Pw[4 * 16 * 36];    // per-wave P, [qrow][slot]
    const int t = threadIdx.x;
    const int w = t >> 6, lane = t & 63, l15 = lane & 15, quad = lane >> 4;
    const int blk = blockIdx.x;
    const int b = blk >> 6, g = (blk >> 3) & 7, c = blk & 7;

    bf16x8 qhf[4], qlf[4];
    {
        size_t base = (size_t)(b * 16 + l15) * DIM + (g * 4 + w) * HD + quad * 8;
        #pragma unroll
        for (int kt = 0; kt < 4; ++kt) {
            qhf[kt] = ldsfrag(qhp + base + kt * 32);
            qlf[kt] = ldsfrag(qlp + base + kt * 32);
        }
    }

    float m_run[4], l_run[4];
    f32x4 oacc[8];
    #pragma unroll
    for (int r = 0; r < 4; ++r) { m_run[r] = -INFINITY; l_run[r] = 0.f; }
    #pragma unroll
    for (int d = 0; d < 8; ++d) oacc[d] = (f32x4){0.f, 0.f, 0.f, 0.f};

    float4 kreg[4], vreg[4];
    auto LOADKV = [&](int it) {
        #pragma unroll
        for (int i = 0; i < 4; ++i) {
            int f = t + i * 256;
            int pos = f >> 5, d0 = (f & 31) << 2;
            int pg = c * CHUNK + it * 32 + pos;
            const float *ksrc, *vsrc;
            if (pg >= START_POS) {
                size_t off = (size_t)(b * 16 + pg - START_POS) * (NKVH * HD) + g * HD + d0;
                ksrc = knew + off; vsrc = vnew + off;
            } else {
                size_t off = ((size_t)(b * MAX_SEQ + pg) * NKVH + g) * HD + d0;
                ksrc = kc + off; vsrc = vc + off;
            }
            kreg[i] = *(const float4*)ksrc;
            vreg[i] = *(const float4*)vsrc;
        }
    };

    unsigned short* phw = Pw + w * 576;

    LOADKV(0);
    for (int it = 0; it < CHUNK / 32; ++it) {
        __syncthreads();
        // K: natural [pos][d], b64 writes, conflict-free
        #pragma unroll
        for (int i = 0; i < 4; ++i) {
            int f = t + i * 256;
            int pos = f >> 5, d0 = (f & 31) << 2;
            ushort4 k4 = make_ushort4(f2bf(kreg[i].x), f2bf(kreg[i].y),
                                      f2bf(kreg[i].z), f2bf(kreg[i].w));
            *(ushort4*)&Kb[pos * 136 + d0] = k4;
        }
        // V: register-gather transpose. Thread holds pos = p0+8i (i=0..3) for fixed d0.
        // slot(pos) = (pos&7)*4 + (pos>>3) => thread's 4 pos -> slots p0*4..p0*4+3.
        {
            int p0 = t >> 5, d0 = (t & 31) << 2;
            #pragma unroll
            for (int j = 0; j < 4; ++j) {
                ushort4 v4 = make_ushort4(f2bf(VCOMP(vreg[0], j)), f2bf(VCOMP(vreg[1], j)),
                                          f2bf(VCOMP(vreg[2], j)), f2bf(VCOMP(vreg[3], j)));
                *(ushort4*)&Vt[(d0 + j) * 36 + p0 * 4] = v4;
            }
        }
        __syncthreads();
        if (it + 1 < CHUNK / 32) LOADKV(it + 1);

        // S = Q K^T (2 n-tiles x 4 k-steps x {hi,lo})
        f32x4 sacc[2];
        sacc[0] = (f32x4){0.f,0.f,0.f,0.f};
        sacc[1] = (f32x4){0.f,0.f,0.f,0.f};
        #pragma unroll
        for (int nt = 0; nt < 2; ++nt)
            #pragma unroll
            for (int kt = 0; kt < 4; ++kt) {
                bf16x8 bh = ldsfrag(&Kb[(nt*16 + l15) * 136 + kt*32 + quad*8]);
                sacc[nt] = MFMA16(qhf[kt], bh, sacc[nt]);
                sacc[nt] = MFMA16(qlf[kt], bh, sacc[nt]);
            }

        // online softmax; q-row = quad*4+r across the quad's 16 lanes
        float e0[4], e1[4], alpha[4];
        #pragma unroll
        for (int r = 0; r < 4; ++r) {
            float s0 = sacc[0][r] * ATT_SCALE;
            float s1 = sacc[1][r] * ATT_SCALE;
            float mx = fmaxf(s0, s1);
            mx = fmaxf(mx, __shfl_xor(mx, 1));
            mx = fmaxf(mx, __shfl_xor(mx, 2));
            mx = fmaxf(mx, __shfl_xor(mx, 4));
            mx = fmaxf(mx, __shfl_xor(mx, 8));
            float mnew = fmaxf(m_run[r], mx);
            alpha[r] = __expf(m_run[r] - mnew);
            e0[r] = __expf(s0 - mnew);
            e1[r] = __expf(s1 - mnew);
            float sum = e0[r] + e1[r];
            sum += __shfl_xor(sum, 1);
            sum += __shfl_xor(sum, 2);
            sum += __shfl_xor(sum, 4);
            sum += __shfl_xor(sum, 8);
            l_run[r] = l_run[r] * alpha[r] + sum;
            m_run[r] = mnew;
        }
        #pragma unroll
        for (int d = 0; d < 8; ++d)
            #pragma unroll
            for (int r = 0; r < 4; ++r) oacc[d][r] *= alpha[r];

        // P -> per-wave LDS at permuted slots: slot = 4*(l15&7) + 2*nt + (l15>>3)
        {
            int slot0 = 4 * (l15 & 7) + (l15 >> 3);
            #pragma unroll
            for (int r = 0; r < 4; ++r) {
                phw[(quad*4 + r) * 36 + slot0]     = f2bf(e0[r]);
                phw[(quad*4 + r) * 36 + slot0 + 2] = f2bf(e1[r]);
            }
        }
        bf16x8 pa = ldsfrag(phw + l15 * 36 + quad * 8);

        // O += P V (8 d-tiles)
        #pragma unroll
        for (int dt = 0; dt < 8; ++dt) {
            bf16x8 vb = ldsfrag(&Vt[(dt*16 + l15) * 36 + quad * 8]);
            oacc[dt] = MFMA16(pa, vb, oacc[dt]);
        }
    }

    #pragma unroll
    for (int dt = 0; dt < 8; ++dt)
        #pragma unroll
        for (int r = 0; r < 4; ++r)
            part_O[((size_t)blk * 64 + w * 16 + quad * 4 + r) * HD + dt * 16 + l15] = oacc[dt][r];
    if (l15 == 0) {
        #pragma unroll
        for (int r = 0; r < 4; ++r) {
            part_m[blk * 64 + w * 16 + quad * 4 + r] = m_run[r];
            part_l[blk * 64 + w * 16 + quad * 4 + r] = l_run[r];
        }
    }
}

__global__ __launch_bounds__(128) void attn_combine_kernel(
    const float* __restrict__ part_O, const float* __restrict__ part_m,
    const float* __restrict__ part_l, unsigned short* __restrict__ ah,
    unsigned short* __restrict__ al)
{
    int bid = blockIdx.x;          // (b*8+g)*64 + row
    int d = threadIdx.x;
    int bg = bid >> 6;
    int row = bid & 63;
    float mc[NCHUNK], lc[NCHUNK];
    float M = -INFINITY;
    #pragma unroll
    for (int cc = 0; cc < NCHUNK; ++cc) {
        mc[cc] = part_m[(bg * NCHUNK + cc) * 64 + row];
        lc[cc] = part_l[(bg * NCHUNK + cc) * 64 + row];
        M = fmaxf(M, mc[cc]);
    }
    float L = 0.f, acc = 0.f;
    #pragma unroll
    for (int cc = 0; cc < NCHUNK; ++cc) {
        float wgt = __expf(mc[cc] - M);
        L += lc[cc] * wgt;
        acc += part_O[((size_t)(bg * NCHUNK + cc) * 64 + row) * HD + d] * wgt;
    }
    int b = bg >> 3, g = bg & 7;
    int r = row >> 4, qp = row & 15;
    float v = acc / L;
    unsigned short h, l; splitbf(v, h, l);
    size_t idx = (size_t)(b * 16 + qp) * DIM + (g * 4 + r) * HD + d;
    ah[idx] = h; al[idx] = l;
}

__global__ __launch_bounds__(256) void oproj_reduce_kernel(
    const float* __restrict__ part, const float* __restrict__ bo,
    float* __restrict__ out)
{
    int gid = blockIdx.x * 256 + threadIdx.x;    // < 128*4096
    int n = gid & 4095;
    float s = 0.f;
    #pragma unroll
    for (int j = 0; j < KS; ++j) s += part[(size_t)j * 524288 + gid];
    out[gid] = s + bo[n];
}

extern "C" void kernel_launch(void* const* d_in, const int* in_sizes, int n_in,
                              void* d_out, int out_size, void* d_ws, size_t ws_size,
                              hipStream_t stream)
{
    const float* x  = (const float*)d_in[0];
    const float* kc = (const float*)d_in[1];
    const float* vc = (const float*)d_in[2];
    const float* Wq = (const float*)d_in[3];
    const float* bq = (const float*)d_in[4];
    const float* Wk = (const float*)d_in[5];
    const float* bk = (const float*)d_in[6];
    const float* Wv = (const float*)d_in[7];
    const float* bv = (const float*)d_in[8];
    const float* Wo = (const float*)d_in[9];
    const float* bo = (const float*)d_in[10];
    float* out = (float*)d_out;
    float* ws  = (float*)d_ws;

    unsigned short* xh = (unsigned short*)(ws + WS_XH);
    unsigned short* xl = (unsigned short*)(ws + WS_XL);
    unsigned short* qh = (unsigned short*)(ws + WS_QH);
    unsigned short* ql = (unsigned short*)(ws + WS_QL);
    unsigned short* ath = (unsigned short*)(ws + WS_ATH);
    unsigned short* atl = (unsigned short*)(ws + WS_ATL);

    split_x_kernel<<<2048, 256, 0, stream>>>(x, xh, xl, 524288);
    qkv_gemm_kernel<<<dim3(96, KS), 256, 0, stream>>>(xh, xl, Wq, Wk, Wv, ws + WS_PART);
    qkv_reduce_kernel<<<3072, 256, 0, stream>>>(ws + WS_PART, bq, bk, bv,
                                                qh, ql, ws + WS_KNEW, ws + WS_VNEW);
    attn_partial3_kernel<<<512, 256, 0, stream>>>(qh, ql, kc, vc,
                                                  ws + WS_KNEW, ws + WS_VNEW,
                                                  ws + WS_PARTO, ws + WS_PM, ws + WS_PL);
    attn_combine_kernel<<<4096, 128, 0, stream>>>(ws + WS_PARTO, ws + WS_PM,
                                                  ws + WS_PL, ath, atl);
    oproj_gemm_kernel<<<dim3(64, KS), 256, 0, stream>>>(ath, atl, Wo, ws + WS_PART);
    oproj_reduce_kernel<<<2048, 256, 0, stream>>>(ws + WS_PART, bo, out);
}